// Round 12
// baseline (4846.644 us; speedup 1.0000x reference)
//
#include <hip/hip_runtime.h>

// ---------------------------------------------------------------------------
// CriticNetwork: GRU over T=256 steps (B=1024, H=256, F=65) + 2-critic MLP.
// Kernel 0 (wib_kernel): pre-convert Wi rows 0..63 -> bf16 B-fragment layout
//   [768 n][72 k] in global workspace (110 KB, L2-resident, shared by all).
// Kernel 1 (gru_kernel): 512 blocks x 512 thr x 2 BATCH EACH, 2 blocks/CU.
//   MODEL FIX (r11): occupancy was LDS-limited (146KB: Wi tile = 110KB of
//   block-identical data), NOT register-limited (320 regs/wave vs 2048/SIMD
//   pool = 6 waves/SIMD possible). Wi moves to global bf16 (read 12x16B/lane
//   /group from L2) -> LDS = 34KB -> 2 blocks/CU co-resident -> two
//   independent recurrence chains interleave per SIMD (the 5175cy serial
//   chain was only 33% MFMA + 23% VALU busy -> huge latency gaps to fill).
//   Per-block structure FROZEN at r11 best (conflict-free XP, fold-after-
//   MFMA, plain 8-deep ks loop, native-cast f2bf, bhn/h in regs).
// Kernel 2 (head_kernel): UNCHANGED (r10 bulk-staged; head-structure-
//   insensitive gap proven = launch/harness overhead).
// ---------------------------------------------------------------------------

#define TSEQ 256
#define DPDIM 64

typedef float f32x4 __attribute__((ext_vector_type(4)));
typedef __bf16 bf16x8 __attribute__((ext_vector_type(8)));
typedef unsigned short ushort8 __attribute__((ext_vector_type(8)));

static __device__ __forceinline__ unsigned short f2bf(float f) {
  return __builtin_bit_cast(unsigned short, (__bf16)f);   // hw RNE cvt
}
static __device__ __forceinline__ float bf2f(unsigned short h) {
  return __builtin_bit_cast(float, ((unsigned)h) << 16);
}
static __device__ __forceinline__ float sigm(float x) {
  return __builtin_amdgcn_rcpf(1.f + __expf(-x));
}
static __device__ __forceinline__ float tanh_fast(float p) {
  float q = __expf(-2.f * fabsf(p));
  float t = (1.f - q) * __builtin_amdgcn_rcpf(1.f + q);
  return __builtin_bit_cast(float, __builtin_bit_cast(unsigned, t) |
                                   (__builtin_bit_cast(unsigned, p) & 0x80000000u));
}

// ---- setup: Wi rows 0..63 -> bf16 [768 n][72 k-stride] in workspace ----
__global__ __launch_bounds__(512) void wib_kernel(
    const float* __restrict__ Wi, unsigned short* __restrict__ Wib)
{
  int idx = blockIdx.x * 512 + threadIdx.x;   // 96 blocks -> 49152 = 64*768
  int k = idx / 768, n = idx - k * 768;
  Wib[n * 72 + k] = f2bf(Wi[idx]);
}

// ---- GRU kernel LDS layout (bytes) — 33,984 total -> 2 blocks/CU ----
#define OFF_XP  0         // xp bf16 [6 j][4 tt][128 col][4 kg] = 24576
#define OFF_H0  24576     // h buf0 bf16 [2 real rows + 1 zero row] stride 544B
#define OFF_H1  26208     // h buf1
#define OFF_BI  27840     // bi f32 [768]
#define OFF_W64 30912     // Wi row 64 (weight channel) f32 [768]
#define LDS_GRU 33984

#define HSTRIDE 544       // h row stride (row bases hit banks {0,8,16})

__global__ __launch_bounds__(512, 4) void gru_kernel(
    const float* __restrict__ particles, const float* __restrict__ weights,
    const float* __restrict__ Wi, const unsigned short* __restrict__ Wib,
    const float* __restrict__ bi, const float* __restrict__ Wh,
    const float* __restrict__ bhn, unsigned short* __restrict__ hT)
{
  extern __shared__ char smem[];
  const int tid  = threadIdx.x;
  const int lane = tid & 63;
  const int w    = tid >> 6;      // wave id 0..7
  const int l15  = lane & 15;
  const int kg   = lane >> 4;     // k-group 0..3
  const int b0   = blockIdx.x * 2;   // 2 batch rows per block

  // ---------------- prologue ----------------
  for (int idx = tid; idx < 768; idx += 512) {
    *(float*)(smem + OFF_BI  + idx * 4) = bi[idx];
    *(float*)(smem + OFF_W64 + idx * 4) = Wi[64 * 768 + idx];
  }
  for (int idx = tid; idx < (2 * 3 * HSTRIDE) / 4; idx += 512)
    ((unsigned*)(smem + OFF_H0))[idx] = 0u;   // h0 = 0 (+ shared zero row 2)

  const int hcol0 = w * 16 + l15;       // p=0 col; p=1 col = hcol0+128
  const float bhn0 = bhn[hcol0];
  const float bhn1 = bhn[hcol0 + 128];

  // Wh -> register B-fragments. Wave w owns N-tiles {w+8j}, j=0..5:
  //   j=0,1 -> r (cols hcol0, hcol0+128); j=2,3 -> z; j=4,5 -> n.
  bf16x8 whb[6][8];
  #pragma unroll
  for (int j = 0; j < 6; ++j) {
    const int tile = w + 8 * j;
    const float* wp = Wh + (size_t)(kg * 8) * 768 + tile * 16 + l15;
    #pragma unroll
    for (int ks = 0; ks < 8; ++ks) {
      ushort8 tmp;
      #pragma unroll
      for (int e = 0; e < 8; ++e)
        tmp[e] = f2bf(wp[(size_t)(ks * 32 + e) * 768]);
      whb[j][ks] = __builtin_bit_cast(bf16x8, tmp);
    }
  }
  __syncthreads();

  // Recurrence A-rows: l15 in {0,4} real (batch = l15>>2, h row l15>>2);
  // all other lanes broadcast-read the shared zero row 2.
  const bool real = ((l15 & 3) == 0) && (l15 < 8);
  const unsigned arow = real
                      ? (unsigned)((l15 >> 2) * HSTRIDE + kg * 16)
                      : (unsigned)(2 * HSTRIDE + kg * 16);

  // xp A-row mapping: row l15 <-> (batch=(l15>>2)&1, time=l15&3) => C reg r
  // of lane (l15,kg) = xp(batch=kg&1, time=t0+r); kg 2,3 park duplicates
  // in their own slots (never read). Addresses clamped in-range.
  const float* pbase = particles +
      ((size_t)(b0 + ((l15 >> 2) & 1)) * TSEQ + (l15 & 3)) * DPDIM + kg * 8;
  const float* wbase = weights + (size_t)(b0 + (kg & 1)) * TSEQ;

  // lane's conflict-free XP slot: + j*4096 + tt*1024
  char* const xpb = smem + OFF_XP + hcol0 * 8 + kg * 2;

  f32x4 acc[6];
  const f32x4 fzero = {0.f, 0.f, 0.f, 0.f};
  float hreg0 = 0.f, hreg1 = 0.f;

  for (int g = 0; g < 64; ++g) {
    const int t0 = g * 4;

    // ---------------- xp phase: project inputs for t0..t0+3 ----------------
    #pragma unroll
    for (int j = 0; j < 6; ++j) acc[j] = fzero;
    #pragma unroll
    for (int ks = 0; ks < 2; ++ks) {
      const float* pp = pbase + (size_t)t0 * DPDIM + ks * 32;
      f32x4 pa = *(const f32x4*)pp;
      f32x4 pb = *(const f32x4*)(pp + 4);
      ushort8 tmp;
      tmp[0] = f2bf(pa[0]); tmp[1] = f2bf(pa[1]); tmp[2] = f2bf(pa[2]); tmp[3] = f2bf(pa[3]);
      tmp[4] = f2bf(pb[0]); tmp[5] = f2bf(pb[1]); tmp[6] = f2bf(pb[2]); tmp[7] = f2bf(pb[3]);
      bf16x8 af = __builtin_bit_cast(bf16x8, tmp);
      #pragma unroll
      for (int j = 0; j < 6; ++j) {
        const int n = hcol0 + 128 * j;
        bf16x8 bf = *(const bf16x8*)((const char*)Wib + n * 144 + ks * 64 + kg * 16);
        acc[j] = __builtin_amdgcn_mfma_f32_16x16x32_bf16(af, bf, acc[j], 0, 0, 0);
      }
    }
    // fold bias + weight-channel, park xp in conflict-free LDS slot
    // (writer lane == only reader lane; banks distinct across the wave).
    {
      f32x4 wv = *(const f32x4*)(wbase + t0);
      #pragma unroll
      for (int j = 0; j < 6; ++j) {
        const int col = hcol0 + 128 * j;
        const float biv  = *(const float*)(smem + OFF_BI  + col * 4);
        const float w64v = *(const float*)(smem + OFF_W64 + col * 4);
        #pragma unroll
        for (int r = 0; r < 4; ++r)
          *(unsigned short*)(xpb + j * 4096 + r * 1024) =
              f2bf(acc[j][r] + biv + wv[r] * w64v);
      }
    }

    // ---------------- 4 GRU steps ----------------
    #pragma unroll
    for (int tt = 0; tt < 4; ++tt) {
      const int t     = t0 + tt;
      const int rboff = (t & 1) ? OFF_H1 : OFF_H0;   // read buffer
      const int wboff = (t & 1) ? OFF_H0 : OFF_H1;   // write buffer
      #pragma unroll
      for (int j = 0; j < 6; ++j) acc[j] = fzero;
      const char* hb = smem + rboff;
      #pragma unroll
      for (int ks = 0; ks < 8; ++ks) {
        bf16x8 af = *(const bf16x8*)(hb + arow + ks * 64);
        #pragma unroll
        for (int j = 0; j < 6; ++j)
          acc[j] = __builtin_amdgcn_mfma_f32_16x16x32_bf16(af, whb[j][ks], acc[j], 0, 0, 0);
      }
      // Gates (reg 0 = batch kg&1; kg>=2 lanes compute but never store).
      float xr0 = bf2f(*(const unsigned short*)(xpb + 0 * 4096 + tt * 1024));
      float xr1 = bf2f(*(const unsigned short*)(xpb + 1 * 4096 + tt * 1024));
      float xz0 = bf2f(*(const unsigned short*)(xpb + 2 * 4096 + tt * 1024));
      float xz1 = bf2f(*(const unsigned short*)(xpb + 3 * 4096 + tt * 1024));
      float xn0 = bf2f(*(const unsigned short*)(xpb + 4 * 4096 + tt * 1024));
      float xn1 = bf2f(*(const unsigned short*)(xpb + 5 * 4096 + tt * 1024));
      float rr0 = sigm(xr0 + acc[0][0]);
      float zz0 = sigm(xz0 + acc[2][0]);
      float nn0 = tanh_fast(xn0 + rr0 * (acc[4][0] + bhn0));
      unsigned short h0u = f2bf(nn0 + zz0 * (hreg0 - nn0));
      hreg0 = bf2f(h0u);
      float rr1 = sigm(xr1 + acc[1][0]);
      float zz1 = sigm(xz1 + acc[3][0]);
      float nn1 = tanh_fast(xn1 + rr1 * (acc[5][0] + bhn1));
      unsigned short h1u = f2bf(nn1 + zz1 * (hreg1 - nn1));
      hreg1 = bf2f(h1u);
      if (kg < 2) {   // only real batch rows; keep zero row 2 intact
        *(unsigned short*)(smem + wboff + kg * HSTRIDE + hcol0 * 2)         = h0u;
        *(unsigned short*)(smem + wboff + kg * HSTRIDE + (hcol0 + 128) * 2) = h1u;
      }
      __syncthreads();
    }
  }

  // epilogue: final h lives in registers -> store directly (real rows only)
  if (kg < 2) {
    hT[(size_t)(b0 + kg) * 256 + hcol0]       = f2bf(hreg0);
    hT[(size_t)(b0 + kg) * 256 + hcol0 + 128] = f2bf(hreg1);
  }
}

// ---- Head kernel LDS layout (bytes; overlayed regions) ----
#define HOFF_W1 0
#define HOFF_WT 135168
#define HOFF_H1 0
#define HOFF_W2 16896
#define HOFF_H2 135168
#define HOFF_B1 155648
#define HOFF_B2 156672
#define HOFF_W3 157696
#define LDS_HEAD 158720

#define HROWS 32          // rows per head block (64 blocks = 32 rows x 2 critics)

__global__ __launch_bounds__(512, 1) void head_kernel(
    const unsigned short* __restrict__ hT, const float* __restrict__ action,
    const float* __restrict__ time_idx, const float* __restrict__ W1,
    const float* __restrict__ b1, const float* __restrict__ W2,
    const float* __restrict__ b2, const float* __restrict__ W3,
    const float* __restrict__ b3, float* __restrict__ out)
{
  extern __shared__ char smem[];
  const int tid  = threadIdx.x;
  const int lane = tid & 63;
  const int w    = tid >> 6;      // wave 0..7; wave w owns N-tiles {2w, 2w+1}
  const int l15  = lane & 15;
  const int kg   = lane >> 4;
  const int c    = blockIdx.x & 1;
  const int rt   = blockIdx.x >> 1;
  const int r0   = rt * HROWS;

  // ---- prologue: biases + zero Wtail region ----
  if (tid < 256) {
    *(float*)(smem + HOFF_B1 + tid * 4) = b1[c * 256 + tid];
    *(float*)(smem + HOFF_B2 + tid * 4) = b2[c * 256 + tid];
    *(float*)(smem + HOFF_W3 + tid * 4) = W3[c * 256 + tid];
  }
  for (int idx = tid; idx < 20480 / 4; idx += 512)
    ((unsigned*)(smem + HOFF_WT))[idx] = 0u;
  __syncthreads();   // zero visible before tail fill (disjoint threads)

  // ---- stage W1: main k=0..255 (vectorized over n) + tail k=256..264 ----
  for (int q = tid; q < 64 * 256; q += 512) {          // 16384 quads, 32 iters
    int k = q >> 6, n0 = (q & 63) * 4;
    f32x4 v = *(const f32x4*)(W1 + ((size_t)c * 265 + k) * 256 + n0);
    char* d = smem + HOFF_W1 + k * 2;
    *(unsigned short*)(d + (size_t)(n0 + 0) * 528) = f2bf(v[0]);
    *(unsigned short*)(d + (size_t)(n0 + 1) * 528) = f2bf(v[1]);
    *(unsigned short*)(d + (size_t)(n0 + 2) * 528) = f2bf(v[2]);
    *(unsigned short*)(d + (size_t)(n0 + 3) * 528) = f2bf(v[3]);
  }
  for (int idx = tid; idx < 9 * 256; idx += 512) {     // tail: 5 iters
    int kk = idx >> 8, n = idx & 255;
    *(unsigned short*)(smem + HOFF_WT + n * 80 + kk * 2) =
        f2bf(W1[((size_t)c * 265 + 256 + kk) * 256 + n]);
  }

  // ---- build the k=256..287 A-fragment tail in registers (per mt) ----
  ushort8 atail[2];
  #pragma unroll
  for (int mt = 0; mt < 2; ++mt) {
    int row = r0 + mt * 16 + l15;
    ushort8 t8 = {0, 0, 0, 0, 0, 0, 0, 0};
    if (kg == 0) {
      f32x4 a0 = *(const f32x4*)(action + (size_t)row * 8);
      f32x4 a1 = *(const f32x4*)(action + (size_t)row * 8 + 4);
      t8[0] = f2bf(a0[0]); t8[1] = f2bf(a0[1]); t8[2] = f2bf(a0[2]); t8[3] = f2bf(a0[3]);
      t8[4] = f2bf(a1[0]); t8[5] = f2bf(a1[1]); t8[6] = f2bf(a1[2]); t8[7] = f2bf(a1[3]);
    } else if (kg == 1) {
      t8[0] = f2bf(time_idx[row] * 0.01f);
    }
    atail[mt] = t8;
  }
  __syncthreads();

  f32x4 acc[2][2];
  const f32x4 fzero = {0.f, 0.f, 0.f, 0.f};

  // ---- layer 1: h1 = relu(x @ W1[c] + b1[c]); x from GLOBAL hT + atail ----
  #pragma unroll
  for (int mt = 0; mt < 2; ++mt)
    #pragma unroll
    for (int i = 0; i < 2; ++i) acc[mt][i] = fzero;
  #pragma unroll
  for (int ks = 0; ks < 8; ++ks) {
    bf16x8 bfr0 = *(const bf16x8*)(smem + HOFF_W1 + ((w * 2 + 0) * 16 + l15) * 528 + ks * 64 + kg * 16);
    bf16x8 bfr1 = *(const bf16x8*)(smem + HOFF_W1 + ((w * 2 + 1) * 16 + l15) * 528 + ks * 64 + kg * 16);
    #pragma unroll
    for (int mt = 0; mt < 2; ++mt) {
      bf16x8 af = *(const bf16x8*)(hT + (size_t)(r0 + mt * 16 + l15) * 256 + ks * 32 + kg * 8);
      acc[mt][0] = __builtin_amdgcn_mfma_f32_16x16x32_bf16(af, bfr0, acc[mt][0], 0, 0, 0);
      acc[mt][1] = __builtin_amdgcn_mfma_f32_16x16x32_bf16(af, bfr1, acc[mt][1], 0, 0, 0);
    }
  }
  {   // tail ks=8: action | time | zero-pad (Wtail region is zero-padded)
    bf16x8 bfr0 = *(const bf16x8*)(smem + HOFF_WT + ((w * 2 + 0) * 16 + l15) * 80 + kg * 16);
    bf16x8 bfr1 = *(const bf16x8*)(smem + HOFF_WT + ((w * 2 + 1) * 16 + l15) * 80 + kg * 16);
    #pragma unroll
    for (int mt = 0; mt < 2; ++mt) {
      bf16x8 af = __builtin_bit_cast(bf16x8, atail[mt]);
      acc[mt][0] = __builtin_amdgcn_mfma_f32_16x16x32_bf16(af, bfr0, acc[mt][0], 0, 0, 0);
      acc[mt][1] = __builtin_amdgcn_mfma_f32_16x16x32_bf16(af, bfr1, acc[mt][1], 0, 0, 0);
    }
  }
  __syncthreads();   // all waves done reading W1/WT before overlaying

  // ---- H1 (overlays W1 rows 0..31) + stage W2 (disjoint region) ----
  #pragma unroll
  for (int mt = 0; mt < 2; ++mt)
    #pragma unroll
    for (int i = 0; i < 2; ++i) {
      int col = (w * 2 + i) * 16 + l15;
      float bv = *(const float*)(smem + HOFF_B1 + col * 4);
      #pragma unroll
      for (int r = 0; r < 4; ++r) {
        float v = acc[mt][i][r] + bv; v = v > 0.f ? v : 0.f;
        *(unsigned short*)(smem + HOFF_H1 + (mt * 16 + kg * 4 + r) * 528 + col * 2) = f2bf(v);
      }
    }
  for (int q = tid; q < 64 * 256; q += 512) {          // stage W2, 32 iters
    int k = q >> 6, n0 = (q & 63) * 4;
    f32x4 v = *(const f32x4*)(W2 + ((size_t)c * 256 + k) * 256 + n0);
    char* d = smem + HOFF_W2 + k * 2;
    *(unsigned short*)(d + (size_t)(n0 + 0) * 528) = f2bf(v[0]);
    *(unsigned short*)(d + (size_t)(n0 + 1) * 528) = f2bf(v[1]);
    *(unsigned short*)(d + (size_t)(n0 + 2) * 528) = f2bf(v[2]);
    *(unsigned short*)(d + (size_t)(n0 + 3) * 528) = f2bf(v[3]);
  }
  __syncthreads();

  // ---- layer 2: h2 = relu(h1 @ W2[c] + b2[c]), K = 256 ----
  #pragma unroll
  for (int mt = 0; mt < 2; ++mt)
    #pragma unroll
    for (int i = 0; i < 2; ++i) acc[mt][i] = fzero;
  #pragma unroll
  for (int ks = 0; ks < 8; ++ks) {
    bf16x8 bfr0 = *(const bf16x8*)(smem + HOFF_W2 + ((w * 2 + 0) * 16 + l15) * 528 + ks * 64 + kg * 16);
    bf16x8 bfr1 = *(const bf16x8*)(smem + HOFF_W2 + ((w * 2 + 1) * 16 + l15) * 528 + ks * 64 + kg * 16);
    #pragma unroll
    for (int mt = 0; mt < 2; ++mt) {
      bf16x8 af = *(const bf16x8*)(smem + HOFF_H1 + (mt * 16 + l15) * 528 + ks * 64 + kg * 16);
      acc[mt][0] = __builtin_amdgcn_mfma_f32_16x16x32_bf16(af, bfr0, acc[mt][0], 0, 0, 0);
      acc[mt][1] = __builtin_amdgcn_mfma_f32_16x16x32_bf16(af, bfr1, acc[mt][1], 0, 0, 0);
    }
  }
  __syncthreads();   // all waves done reading W2 before overlaying H2

  #pragma unroll
  for (int mt = 0; mt < 2; ++mt)
    #pragma unroll
    for (int i = 0; i < 2; ++i) {
      int col = (w * 2 + i) * 16 + l15;
      float bv = *(const float*)(smem + HOFF_B2 + col * 4);
      #pragma unroll
      for (int r = 0; r < 4; ++r) {
        float v = acc[mt][i][r] + bv; v = v > 0.f ? v : 0.f;
        *(unsigned short*)(smem + HOFF_H2 + (mt * 16 + kg * 4 + r) * 528 + col * 2) = f2bf(v);
      }
    }
  __syncthreads();

  // ---- layer 3: v = h2 @ W3[c] + b3[c] (VALU dot, 4 threads/row) ----
  {
    int row = tid >> 2, q = tid & 3;
    if (row < HROWS) {
      float s = 0.f;
      #pragma unroll
      for (int i = 0; i < 16; ++i) {
        uint2 hh = *(const uint2*)(smem + HOFF_H2 + row * 528 + (q * 64 + i * 4) * 2);
        const float* w3p = (const float*)(smem + HOFF_W3) + q * 64 + i * 4;
        s += bf2f((unsigned short)hh.x)         * w3p[0];
        s += bf2f((unsigned short)(hh.x >> 16)) * w3p[1];
        s += bf2f((unsigned short)hh.y)         * w3p[2];
        s += bf2f((unsigned short)(hh.y >> 16)) * w3p[3];
      }
      s += __shfl_xor(s, 1);
      s += __shfl_xor(s, 2);
      if (q == 0) out[(r0 + row) * 2 + c] = s + b3[c];
    }
  }
}

extern "C" void kernel_launch(void* const* d_in, const int* in_sizes, int n_in,
                              void* d_out, int out_size, void* d_ws, size_t ws_size,
                              hipStream_t stream) {
  const float* particles = (const float*)d_in[0];
  const float* weights   = (const float*)d_in[1];
  const float* action    = (const float*)d_in[2];
  const float* time_idx  = (const float*)d_in[3];
  const float* Wi        = (const float*)d_in[4];
  const float* bi        = (const float*)d_in[5];
  const float* Wh        = (const float*)d_in[6];
  const float* bhn       = (const float*)d_in[7];
  const float* W1        = (const float*)d_in[8];
  const float* b1        = (const float*)d_in[9];
  const float* W2        = (const float*)d_in[10];
  const float* b2        = (const float*)d_in[11];
  const float* W3        = (const float*)d_in[12];
  const float* b3        = (const float*)d_in[13];
  unsigned short* hT  = (unsigned short*)d_ws;                      // 512 KB
  unsigned short* Wib = (unsigned short*)((char*)d_ws + 524288);    // 96 KB
  float* out = (float*)d_out;

  (void)hipFuncSetAttribute((const void*)gru_kernel,
                            hipFuncAttributeMaxDynamicSharedMemorySize, LDS_GRU);
  (void)hipFuncSetAttribute((const void*)head_kernel,
                            hipFuncAttributeMaxDynamicSharedMemorySize, LDS_HEAD);

  hipLaunchKernelGGL(wib_kernel, dim3(96), dim3(512), 0, stream, Wi, Wib);
  hipLaunchKernelGGL(gru_kernel, dim3(512), dim3(512), LDS_GRU, stream,
                     particles, weights, Wi, Wib, bi, Wh, bhn, hT);
  hipLaunchKernelGGL(head_kernel, dim3(64), dim3(512), LDS_HEAD, stream,
                     hT, action, time_idx, W1, b1, W2, b2, W3, b3, out);
}

// Round 13
// 647.708 us; speedup vs baseline: 7.4828x; 7.4828x over previous
//
#include <hip/hip_runtime.h>

// ---------------------------------------------------------------------------
// CriticNetwork: GRU over T=256 steps (B=1024, H=256, F=65) + 2-critic MLP.
// Kernel 1 (gru_kernel): FROZEN at r11 best (552us gru; 649us total).
//   REGISTER MODEL (final, r5+r12 measured): pool = 512 regs/lane/SIMD.
//   Register-resident Wh admits exactly ONE occupancy point: 8 waves x
//   2/SIMD x 256 regs (whb=192). 4/SIMD caps at 128 -> whb spills -> 16 GB
//   scratch traffic (r12: 4.7ms). 3/SIMD unreachable. Do not retry.
//   Structure: conflict-free XP layout [j][tt][col][kg], fold-after-MFMA,
//   plain 8-deep compiler-scheduled ks loop, native-cast f2bf (hw
//   v_cvt_pk_bf16_f32; r11: -48us + less spill), bhn/h in regs, fake
//   A-lanes broadcast-read shared zero row 4.
// Kernel 2 (head_kernel): r10 bulk-staged (total-gru gap ~95us proven
//   insensitive to head structure -> launch/harness overhead).
// ---------------------------------------------------------------------------

#define TSEQ 256
#define DPDIM 64

typedef float f32x4 __attribute__((ext_vector_type(4)));
typedef __bf16 bf16x8 __attribute__((ext_vector_type(8)));
typedef unsigned short ushort8 __attribute__((ext_vector_type(8)));

static __device__ __forceinline__ unsigned short f2bf(float f) {
  return __builtin_bit_cast(unsigned short, (__bf16)f);   // hw RNE cvt
}
static __device__ __forceinline__ float bf2f(unsigned short h) {
  return __builtin_bit_cast(float, ((unsigned)h) << 16);
}
static __device__ __forceinline__ float sigm(float x) {
  return __builtin_amdgcn_rcpf(1.f + __expf(-x));
}
static __device__ __forceinline__ float tanh_fast(float p) {
  float q = __expf(-2.f * fabsf(p));
  float t = (1.f - q) * __builtin_amdgcn_rcpf(1.f + q);
  return __builtin_bit_cast(float, __builtin_bit_cast(unsigned, t) |
                                   (__builtin_bit_cast(unsigned, p) & 0x80000000u));
}

// ---- GRU kernel LDS layout (bytes) ----
#define OFF_WIT 0         // Wi transposed bf16 [768 n][72 k-stride] = 768*144
#define OFF_XP  110592    // xp bf16 [6 j][4 tt][128 col][4 kg] = 24576
#define OFF_H0  135168    // h buf0 bf16 [4 real rows + 1 zero row][272] stride 544B
#define OFF_H1  137888    // h buf1
#define OFF_BI  140608    // bi f32 [768]
#define OFF_W64 143680    // Wi row 64 (weight channel) f32 [768]
#define LDS_GRU 146752

#define HSTRIDE 544       // h row stride (row bases hit banks {0,8,16,24})

__global__ __launch_bounds__(512, 2) void gru_kernel(
    const float* __restrict__ particles, const float* __restrict__ weights,
    const float* __restrict__ Wi, const float* __restrict__ bi,
    const float* __restrict__ Wh, const float* __restrict__ bhn,
    unsigned short* __restrict__ hT)
{
  extern __shared__ char smem[];
  const int tid  = threadIdx.x;
  const int lane = tid & 63;
  const int w    = tid >> 6;      // wave id 0..7
  const int l15  = lane & 15;
  const int kg   = lane >> 4;     // k-group 0..3
  const int b0   = blockIdx.x * 4;

  // ---------------- prologue ----------------
  for (int idx = tid; idx < 64 * 768; idx += 512) {
    int k = idx / 768, n = idx - k * 768;
    *(unsigned short*)(smem + OFF_WIT + n * 144 + k * 2) = f2bf(Wi[idx]);
  }
  for (int idx = tid; idx < 768; idx += 512) {
    *(float*)(smem + OFF_BI  + idx * 4) = bi[idx];
    *(float*)(smem + OFF_W64 + idx * 4) = Wi[64 * 768 + idx];
  }
  for (int idx = tid; idx < (2 * 5 * HSTRIDE) / 4; idx += 512)
    ((unsigned*)(smem + OFF_H0))[idx] = 0u;   // h0 = 0 (+ shared zero row 4)

  const int hcol0 = w * 16 + l15;       // p=0 col; p=1 col = hcol0+128
  const float bhn0 = bhn[hcol0];
  const float bhn1 = bhn[hcol0 + 128];

  // Wh -> register B-fragments. Wave w owns N-tiles {w+8j}, j=0..5:
  //   j=0,1 -> r (cols hcol0, hcol0+128); j=2,3 -> z; j=4,5 -> n.
  bf16x8 whb[6][8];
  #pragma unroll
  for (int j = 0; j < 6; ++j) {
    const int tile = w + 8 * j;
    const float* wp = Wh + (size_t)(kg * 8) * 768 + tile * 16 + l15;
    #pragma unroll
    for (int ks = 0; ks < 8; ++ks) {
      ushort8 tmp;
      #pragma unroll
      for (int e = 0; e < 8; ++e)
        tmp[e] = f2bf(wp[(size_t)(ks * 32 + e) * 768]);
      whb[j][ks] = __builtin_bit_cast(bf16x8, tmp);
    }
  }
  __syncthreads();

  // A-fragment source for the recurrence: M-row l15 is real iff l15%4==0
  // (batch = l15>>2, h row l15>>2); fake lanes read the shared zero row 4
  // (same-address broadcast; ~2-way max conflict).
  const unsigned arow = ((l15 & 3) == 0)
                      ? (unsigned)((l15 >> 2) * HSTRIDE + kg * 16)
                      : (unsigned)(4 * HSTRIDE + kg * 16);

  // xp A-row mapping: row l15 <-> (batch=l15>>2, time=l15&3) => C reg r of
  // lane (l15,kg) = xp(batch=kg, time=t0+r), i.e. writer lane == reader lane.
  const float* pbase = particles +
      ((size_t)(b0 + (l15 >> 2)) * TSEQ + (l15 & 3)) * DPDIM + kg * 8;
  const float* wbase = weights + (size_t)(b0 + kg) * TSEQ;

  // lane's conflict-free XP slot: + j*4096 + tt*1024
  char* const xpb = smem + OFF_XP + hcol0 * 8 + kg * 2;

  f32x4 acc[6];
  const f32x4 fzero = {0.f, 0.f, 0.f, 0.f};
  float hreg0 = 0.f, hreg1 = 0.f;

  for (int g = 0; g < 64; ++g) {
    const int t0 = g * 4;

    // ---------------- xp phase: project inputs for t0..t0+3 ----------------
    #pragma unroll
    for (int j = 0; j < 6; ++j) acc[j] = fzero;
    #pragma unroll
    for (int ks = 0; ks < 2; ++ks) {
      const float* pp = pbase + (size_t)t0 * DPDIM + ks * 32;
      f32x4 pa = *(const f32x4*)pp;
      f32x4 pb = *(const f32x4*)(pp + 4);
      ushort8 tmp;
      tmp[0] = f2bf(pa[0]); tmp[1] = f2bf(pa[1]); tmp[2] = f2bf(pa[2]); tmp[3] = f2bf(pa[3]);
      tmp[4] = f2bf(pb[0]); tmp[5] = f2bf(pb[1]); tmp[6] = f2bf(pb[2]); tmp[7] = f2bf(pb[3]);
      bf16x8 af = __builtin_bit_cast(bf16x8, tmp);
      #pragma unroll
      for (int j = 0; j < 6; ++j) {
        const int n = hcol0 + 128 * j;
        bf16x8 bf = *(const bf16x8*)(smem + OFF_WIT + n * 144 + ks * 64 + kg * 16);
        acc[j] = __builtin_amdgcn_mfma_f32_16x16x32_bf16(af, bf, acc[j], 0, 0, 0);
      }
    }
    // fold bias + weight-channel, park xp in conflict-free LDS slot
    // (writer lane == only reader lane; banks distinct across the wave).
    {
      f32x4 wv = *(const f32x4*)(wbase + t0);
      #pragma unroll
      for (int j = 0; j < 6; ++j) {
        const int col = hcol0 + 128 * j;
        const float biv  = *(const float*)(smem + OFF_BI  + col * 4);
        const float w64v = *(const float*)(smem + OFF_W64 + col * 4);
        #pragma unroll
        for (int r = 0; r < 4; ++r)
          *(unsigned short*)(xpb + j * 4096 + r * 1024) =
              f2bf(acc[j][r] + biv + wv[r] * w64v);
      }
    }

    // ---------------- 4 GRU steps ----------------
    #pragma unroll
    for (int tt = 0; tt < 4; ++tt) {
      const int t     = t0 + tt;
      const int rboff = (t & 1) ? OFF_H1 : OFF_H0;   // read buffer
      const int wboff = (t & 1) ? OFF_H0 : OFF_H1;   // write buffer
      #pragma unroll
      for (int j = 0; j < 6; ++j) acc[j] = fzero;
      const char* hb = smem + rboff;
      #pragma unroll
      for (int ks = 0; ks < 8; ++ks) {
        bf16x8 af = *(const bf16x8*)(hb + arow + ks * 64);
        #pragma unroll
        for (int j = 0; j < 6; ++j)
          acc[j] = __builtin_amdgcn_mfma_f32_16x16x32_bf16(af, whb[j][ks], acc[j], 0, 0, 0);
      }
      // Gates (reg 0 = batch kg): xp from conflict-free LDS; bhn/h in regs.
      float xr0 = bf2f(*(const unsigned short*)(xpb + 0 * 4096 + tt * 1024));
      float xr1 = bf2f(*(const unsigned short*)(xpb + 1 * 4096 + tt * 1024));
      float xz0 = bf2f(*(const unsigned short*)(xpb + 2 * 4096 + tt * 1024));
      float xz1 = bf2f(*(const unsigned short*)(xpb + 3 * 4096 + tt * 1024));
      float xn0 = bf2f(*(const unsigned short*)(xpb + 4 * 4096 + tt * 1024));
      float xn1 = bf2f(*(const unsigned short*)(xpb + 5 * 4096 + tt * 1024));
      float rr0 = sigm(xr0 + acc[0][0]);
      float zz0 = sigm(xz0 + acc[2][0]);
      float nn0 = tanh_fast(xn0 + rr0 * (acc[4][0] + bhn0));
      unsigned short h0u = f2bf(nn0 + zz0 * (hreg0 - nn0));
      hreg0 = bf2f(h0u);
      float rr1 = sigm(xr1 + acc[1][0]);
      float zz1 = sigm(xz1 + acc[3][0]);
      float nn1 = tanh_fast(xn1 + rr1 * (acc[5][0] + bhn1));
      unsigned short h1u = f2bf(nn1 + zz1 * (hreg1 - nn1));
      hreg1 = bf2f(h1u);
      *(unsigned short*)(smem + wboff + kg * HSTRIDE + hcol0 * 2)         = h0u;
      *(unsigned short*)(smem + wboff + kg * HSTRIDE + (hcol0 + 128) * 2) = h1u;
      __syncthreads();
    }
  }

  // epilogue: final h lives in registers -> store directly
  hT[(size_t)(b0 + kg) * 256 + hcol0]       = f2bf(hreg0);
  hT[(size_t)(b0 + kg) * 256 + hcol0 + 128] = f2bf(hreg1);
}

// ---- Head kernel LDS layout (bytes; overlayed regions) ----
#define HOFF_W1 0
#define HOFF_WT 135168
#define HOFF_H1 0
#define HOFF_W2 16896
#define HOFF_H2 135168
#define HOFF_B1 155648
#define HOFF_B2 156672
#define HOFF_W3 157696
#define LDS_HEAD 158720

#define HROWS 32          // rows per head block (64 blocks = 32 rows x 2 critics)

__global__ __launch_bounds__(512, 1) void head_kernel(
    const unsigned short* __restrict__ hT, const float* __restrict__ action,
    const float* __restrict__ time_idx, const float* __restrict__ W1,
    const float* __restrict__ b1, const float* __restrict__ W2,
    const float* __restrict__ b2, const float* __restrict__ W3,
    const float* __restrict__ b3, float* __restrict__ out)
{
  extern __shared__ char smem[];
  const int tid  = threadIdx.x;
  const int lane = tid & 63;
  const int w    = tid >> 6;      // wave 0..7; wave w owns N-tiles {2w, 2w+1}
  const int l15  = lane & 15;
  const int kg   = lane >> 4;
  const int c    = blockIdx.x & 1;
  const int rt   = blockIdx.x >> 1;
  const int r0   = rt * HROWS;

  // ---- prologue: biases + zero Wtail region ----
  if (tid < 256) {
    *(float*)(smem + HOFF_B1 + tid * 4) = b1[c * 256 + tid];
    *(float*)(smem + HOFF_B2 + tid * 4) = b2[c * 256 + tid];
    *(float*)(smem + HOFF_W3 + tid * 4) = W3[c * 256 + tid];
  }
  for (int idx = tid; idx < 20480 / 4; idx += 512)
    ((unsigned*)(smem + HOFF_WT))[idx] = 0u;
  __syncthreads();   // zero visible before tail fill (disjoint threads)

  // ---- stage W1: main k=0..255 (vectorized over n) + tail k=256..264 ----
  for (int q = tid; q < 64 * 256; q += 512) {          // 16384 quads, 32 iters
    int k = q >> 6, n0 = (q & 63) * 4;
    f32x4 v = *(const f32x4*)(W1 + ((size_t)c * 265 + k) * 256 + n0);
    char* d = smem + HOFF_W1 + k * 2;
    *(unsigned short*)(d + (size_t)(n0 + 0) * 528) = f2bf(v[0]);
    *(unsigned short*)(d + (size_t)(n0 + 1) * 528) = f2bf(v[1]);
    *(unsigned short*)(d + (size_t)(n0 + 2) * 528) = f2bf(v[2]);
    *(unsigned short*)(d + (size_t)(n0 + 3) * 528) = f2bf(v[3]);
  }
  for (int idx = tid; idx < 9 * 256; idx += 512) {     // tail: 5 iters
    int kk = idx >> 8, n = idx & 255;
    *(unsigned short*)(smem + HOFF_WT + n * 80 + kk * 2) =
        f2bf(W1[((size_t)c * 265 + 256 + kk) * 256 + n]);
  }

  // ---- build the k=256..287 A-fragment tail in registers (per mt) ----
  ushort8 atail[2];
  #pragma unroll
  for (int mt = 0; mt < 2; ++mt) {
    int row = r0 + mt * 16 + l15;
    ushort8 t8 = {0, 0, 0, 0, 0, 0, 0, 0};
    if (kg == 0) {
      f32x4 a0 = *(const f32x4*)(action + (size_t)row * 8);
      f32x4 a1 = *(const f32x4*)(action + (size_t)row * 8 + 4);
      t8[0] = f2bf(a0[0]); t8[1] = f2bf(a0[1]); t8[2] = f2bf(a0[2]); t8[3] = f2bf(a0[3]);
      t8[4] = f2bf(a1[0]); t8[5] = f2bf(a1[1]); t8[6] = f2bf(a1[2]); t8[7] = f2bf(a1[3]);
    } else if (kg == 1) {
      t8[0] = f2bf(time_idx[row] * 0.01f);
    }
    atail[mt] = t8;
  }
  __syncthreads();

  f32x4 acc[2][2];
  const f32x4 fzero = {0.f, 0.f, 0.f, 0.f};

  // ---- layer 1: h1 = relu(x @ W1[c] + b1[c]); x from GLOBAL hT + atail ----
  #pragma unroll
  for (int mt = 0; mt < 2; ++mt)
    #pragma unroll
    for (int i = 0; i < 2; ++i) acc[mt][i] = fzero;
  #pragma unroll
  for (int ks = 0; ks < 8; ++ks) {
    bf16x8 bfr0 = *(const bf16x8*)(smem + HOFF_W1 + ((w * 2 + 0) * 16 + l15) * 528 + ks * 64 + kg * 16);
    bf16x8 bfr1 = *(const bf16x8*)(smem + HOFF_W1 + ((w * 2 + 1) * 16 + l15) * 528 + ks * 64 + kg * 16);
    #pragma unroll
    for (int mt = 0; mt < 2; ++mt) {
      bf16x8 af = *(const bf16x8*)(hT + (size_t)(r0 + mt * 16 + l15) * 256 + ks * 32 + kg * 8);
      acc[mt][0] = __builtin_amdgcn_mfma_f32_16x16x32_bf16(af, bfr0, acc[mt][0], 0, 0, 0);
      acc[mt][1] = __builtin_amdgcn_mfma_f32_16x16x32_bf16(af, bfr1, acc[mt][1], 0, 0, 0);
    }
  }
  {   // tail ks=8: action | time | zero-pad (Wtail region is zero-padded)
    bf16x8 bfr0 = *(const bf16x8*)(smem + HOFF_WT + ((w * 2 + 0) * 16 + l15) * 80 + kg * 16);
    bf16x8 bfr1 = *(const bf16x8*)(smem + HOFF_WT + ((w * 2 + 1) * 16 + l15) * 80 + kg * 16);
    #pragma unroll
    for (int mt = 0; mt < 2; ++mt) {
      bf16x8 af = __builtin_bit_cast(bf16x8, atail[mt]);
      acc[mt][0] = __builtin_amdgcn_mfma_f32_16x16x32_bf16(af, bfr0, acc[mt][0], 0, 0, 0);
      acc[mt][1] = __builtin_amdgcn_mfma_f32_16x16x32_bf16(af, bfr1, acc[mt][1], 0, 0, 0);
    }
  }
  __syncthreads();   // all waves done reading W1/WT before overlaying

  // ---- H1 (overlays W1 rows 0..31) + stage W2 (disjoint region) ----
  #pragma unroll
  for (int mt = 0; mt < 2; ++mt)
    #pragma unroll
    for (int i = 0; i < 2; ++i) {
      int col = (w * 2 + i) * 16 + l15;
      float bv = *(const float*)(smem + HOFF_B1 + col * 4);
      #pragma unroll
      for (int r = 0; r < 4; ++r) {
        float v = acc[mt][i][r] + bv; v = v > 0.f ? v : 0.f;
        *(unsigned short*)(smem + HOFF_H1 + (mt * 16 + kg * 4 + r) * 528 + col * 2) = f2bf(v);
      }
    }
  for (int q = tid; q < 64 * 256; q += 512) {          // stage W2, 32 iters
    int k = q >> 6, n0 = (q & 63) * 4;
    f32x4 v = *(const f32x4*)(W2 + ((size_t)c * 256 + k) * 256 + n0);
    char* d = smem + HOFF_W2 + k * 2;
    *(unsigned short*)(d + (size_t)(n0 + 0) * 528) = f2bf(v[0]);
    *(unsigned short*)(d + (size_t)(n0 + 1) * 528) = f2bf(v[1]);
    *(unsigned short*)(d + (size_t)(n0 + 2) * 528) = f2bf(v[2]);
    *(unsigned short*)(d + (size_t)(n0 + 3) * 528) = f2bf(v[3]);
  }
  __syncthreads();

  // ---- layer 2: h2 = relu(h1 @ W2[c] + b2[c]), K = 256 ----
  #pragma unroll
  for (int mt = 0; mt < 2; ++mt)
    #pragma unroll
    for (int i = 0; i < 2; ++i) acc[mt][i] = fzero;
  #pragma unroll
  for (int ks = 0; ks < 8; ++ks) {
    bf16x8 bfr0 = *(const bf16x8*)(smem + HOFF_W2 + ((w * 2 + 0) * 16 + l15) * 528 + ks * 64 + kg * 16);
    bf16x8 bfr1 = *(const bf16x8*)(smem + HOFF_W2 + ((w * 2 + 1) * 16 + l15) * 528 + ks * 64 + kg * 16);
    #pragma unroll
    for (int mt = 0; mt < 2; ++mt) {
      bf16x8 af = *(const bf16x8*)(smem + HOFF_H1 + (mt * 16 + l15) * 528 + ks * 64 + kg * 16);
      acc[mt][0] = __builtin_amdgcn_mfma_f32_16x16x32_bf16(af, bfr0, acc[mt][0], 0, 0, 0);
      acc[mt][1] = __builtin_amdgcn_mfma_f32_16x16x32_bf16(af, bfr1, acc[mt][1], 0, 0, 0);
    }
  }
  __syncthreads();   // all waves done reading W2 before overlaying H2

  #pragma unroll
  for (int mt = 0; mt < 2; ++mt)
    #pragma unroll
    for (int i = 0; i < 2; ++i) {
      int col = (w * 2 + i) * 16 + l15;
      float bv = *(const float*)(smem + HOFF_B2 + col * 4);
      #pragma unroll
      for (int r = 0; r < 4; ++r) {
        float v = acc[mt][i][r] + bv; v = v > 0.f ? v : 0.f;
        *(unsigned short*)(smem + HOFF_H2 + (mt * 16 + kg * 4 + r) * 528 + col * 2) = f2bf(v);
      }
    }
  __syncthreads();

  // ---- layer 3: v = h2 @ W3[c] + b3[c] (VALU dot, 4 threads/row) ----
  {
    int row = tid >> 2, q = tid & 3;
    if (row < HROWS) {
      float s = 0.f;
      #pragma unroll
      for (int i = 0; i < 16; ++i) {
        uint2 hh = *(const uint2*)(smem + HOFF_H2 + row * 528 + (q * 64 + i * 4) * 2);
        const float* w3p = (const float*)(smem + HOFF_W3) + q * 64 + i * 4;
        s += bf2f((unsigned short)hh.x)         * w3p[0];
        s += bf2f((unsigned short)(hh.x >> 16)) * w3p[1];
        s += bf2f((unsigned short)hh.y)         * w3p[2];
        s += bf2f((unsigned short)(hh.y >> 16)) * w3p[3];
      }
      s += __shfl_xor(s, 1);
      s += __shfl_xor(s, 2);
      if (q == 0) out[(r0 + row) * 2 + c] = s + b3[c];
    }
  }
}

extern "C" void kernel_launch(void* const* d_in, const int* in_sizes, int n_in,
                              void* d_out, int out_size, void* d_ws, size_t ws_size,
                              hipStream_t stream) {
  const float* particles = (const float*)d_in[0];
  const float* weights   = (const float*)d_in[1];
  const float* action    = (const float*)d_in[2];
  const float* time_idx  = (const float*)d_in[3];
  const float* Wi        = (const float*)d_in[4];
  const float* bi        = (const float*)d_in[5];
  const float* Wh        = (const float*)d_in[6];
  const float* bhn       = (const float*)d_in[7];
  const float* W1        = (const float*)d_in[8];
  const float* b1        = (const float*)d_in[9];
  const float* W2        = (const float*)d_in[10];
  const float* b2        = (const float*)d_in[11];
  const float* W3        = (const float*)d_in[12];
  const float* b3        = (const float*)d_in[13];
  unsigned short* hT = (unsigned short*)d_ws;   // [1024][256] bf16
  float* out = (float*)d_out;

  (void)hipFuncSetAttribute((const void*)gru_kernel,
                            hipFuncAttributeMaxDynamicSharedMemorySize, LDS_GRU);
  (void)hipFuncSetAttribute((const void*)head_kernel,
                            hipFuncAttributeMaxDynamicSharedMemorySize, LDS_HEAD);

  hipLaunchKernelGGL(gru_kernel, dim3(256), dim3(512), LDS_GRU, stream,
                     particles, weights, Wi, bi, Wh, bhn, hT);
  hipLaunchKernelGGL(head_kernel, dim3(64), dim3(512), LDS_HEAD, stream,
                     hT, action, time_idx, W1, b1, W2, b2, W3, b3, out);
}